// Round 1
// baseline (1793.807 us; speedup 1.0000x reference)
//
#include <hip/hip_runtime.h>
#include <math.h>

// pGNN on MI355X. Sizes: N=100000 nodes, E=1.6M edges, IN=256, HID=64, OUT=40.
// MU=0.1, P=2.5, K=2. All f32. edge_index passed as int32 (harness converts).

#define HIDC 64

// ---------------- degree ----------------
__global__ void k_deg(const int* __restrict__ col, int* __restrict__ deg, int E) {
    int e = blockIdx.x * blockDim.x + threadIdx.x;
    if (e < E) atomicAdd(&deg[col[e]], 1);
}

__global__ void k_dis(const int* __restrict__ deg, float* __restrict__ dis, int N) {
    int i = blockIdx.x * blockDim.x + threadIdx.x;
    if (i < N) {
        int d = deg[i];
        dis[i] = (d > 0) ? rsqrtf((float)d) : 0.0f;
    }
}

// ---------------- h = relu(x @ W1 + b1) ----------------
// x: N x 256 row-major, W1: 256 x 64 row-major.
// Block = 256 threads = 16 rows x 16 threads; each thread computes 4 columns.
__global__ void k_mlp1(const float* __restrict__ x, const float* __restrict__ W1,
                       const float* __restrict__ b1, float* __restrict__ h, int N) {
    __shared__ float xs[16][257];   // +1 pad: xs[r][k] bank = (257r+k)%32, distinct per r
    const int tid = threadIdx.x;
    const int rowBase = blockIdx.x * 16;
    // cooperative load: 16 rows x 256 floats = 1024 float4 slots
    #pragma unroll
    for (int i = 0; i < 4; ++i) {
        int slot = tid + 256 * i;
        int rl = slot >> 6;
        int off = (slot & 63) * 4;
        int grow = rowBase + rl;
        float4 v = make_float4(0.f, 0.f, 0.f, 0.f);
        if (grow < N) v = *(const float4*)(x + (size_t)grow * 256 + off);
        xs[rl][off]     = v.x;
        xs[rl][off + 1] = v.y;
        xs[rl][off + 2] = v.z;
        xs[rl][off + 3] = v.w;
    }
    __syncthreads();
    const int rl = tid >> 4;            // 0..15
    const int c4 = (tid & 15) * 4;      // 0,4,...,60
    const int row = rowBase + rl;
    if (row >= N) return;
    float a0 = b1[c4], a1 = b1[c4 + 1], a2 = b1[c4 + 2], a3 = b1[c4 + 3];
    #pragma unroll 8
    for (int k = 0; k < 256; ++k) {
        float xv = xs[rl][k];
        float4 w = *(const float4*)(W1 + k * HIDC + c4);
        a0 = fmaf(xv, w.x, a0);
        a1 = fmaf(xv, w.y, a1);
        a2 = fmaf(xv, w.z, a2);
        a3 = fmaf(xv, w.w, a3);
    }
    float4 r;
    r.x = fmaxf(a0, 0.f); r.y = fmaxf(a1, 0.f);
    r.z = fmaxf(a2, 0.f); r.w = fmaxf(a3, 0.f);
    *(float4*)(h + (size_t)row * HIDC + c4) = r;
}

// ---------------- calc_M: per-edge p-norm weight + segment_sum by col ----------------
// wave per edge; lane j handles feature dim j.
__global__ void k_calcM(const int* __restrict__ row, const int* __restrict__ col,
                        const float* __restrict__ dis, const float* __restrict__ cur,
                        float* __restrict__ Mbuf, float* __restrict__ segM, int E) {
    int wave = (int)((blockIdx.x * (size_t)blockDim.x + threadIdx.x) >> 6);
    int lane = threadIdx.x & 63;
    if (wave >= E) return;
    int r = row[wave], c = col[wave];
    float dr = dis[r], dc = dis[c];
    float d = dr * cur[(size_t)r * HIDC + lane] - dc * cur[(size_t)c * HIDC + lane];
    float s = d * d;
    #pragma unroll
    for (int off = 32; off; off >>= 1) s += __shfl_xor(s, off, 64);
    if (lane == 0) {
        float gn = sqrtf(s);          // grad_norm
        float m = sqrtf(gn);          // grad_norm^(P-2) with P=2.5
        if (isinf(m)) m = 0.0f;
        Mbuf[wave] = m;
        atomicAdd(&segM[c], m);
    }
}

// ---------------- alpha ----------------
__global__ void k_alpha(const float* __restrict__ dis, const float* __restrict__ segM,
                        float* __restrict__ alpha, int N) {
    int i = blockIdx.x * blockDim.x + threadIdx.x;
    if (i < N) {
        float d2 = dis[i] * dis[i];
        alpha[i] = 1.0f / (d2 * segM[i] + 0.08f);   // 2*MU/P = 0.08
    }
}

// ---------------- out_next = beta * h (init before scatter) ----------------
__global__ void k_init(const float* __restrict__ alpha, const float* __restrict__ h,
                       float* __restrict__ outNext, size_t total) {
    size_t idx = blockIdx.x * (size_t)blockDim.x + threadIdx.x;
    if (idx < total) {
        int node = (int)(idx >> 6);
        outNext[idx] = 0.16f * alpha[node] * h[idx];   // 4*MU/P = 0.16
    }
}

// ---------------- scatter: out_next[col] += M_ * cur[row] ----------------
__global__ void k_scatter(const int* __restrict__ row, const int* __restrict__ col,
                          const float* __restrict__ dis, const float* __restrict__ alpha,
                          const float* __restrict__ Mbuf, const float* __restrict__ cur,
                          float* __restrict__ outNext, int E) {
    int wave = (int)((blockIdx.x * (size_t)blockDim.x + threadIdx.x) >> 6);
    int lane = threadIdx.x & 63;
    if (wave >= E) return;
    int r = row[wave], c = col[wave];
    float m_ = alpha[r] * dis[r] * Mbuf[wave] * dis[c];
    atomicAdd(&outNext[(size_t)c * HIDC + lane], m_ * cur[(size_t)r * HIDC + lane]);
}

// ---------------- head: log_softmax(out @ W2 + b2) ----------------
// wave per row; lanes 0..OUT-1 hold one logit each.
__global__ void k_head(const float* __restrict__ out, const float* __restrict__ W2,
                       const float* __restrict__ b2, float* __restrict__ y,
                       int N, int OUT) {
    int wave = (int)((blockIdx.x * (size_t)blockDim.x + threadIdx.x) >> 6);
    int lane = threadIdx.x & 63;
    if (wave >= N) return;
    float acc = 0.0f;
    if (lane < OUT) {
        acc = b2[lane];
        #pragma unroll 8
        for (int k = 0; k < HIDC; ++k)
            acc = fmaf(out[(size_t)wave * HIDC + k], W2[k * OUT + lane], acc);
    }
    float v = (lane < OUT) ? acc : -INFINITY;
    #pragma unroll
    for (int off = 32; off; off >>= 1) v = fmaxf(v, __shfl_xor(v, off, 64));
    float ex = (lane < OUT) ? __expf(acc - v) : 0.0f;
    float s = ex;
    #pragma unroll
    for (int off = 32; off; off >>= 1) s += __shfl_xor(s, off, 64);
    if (lane < OUT) y[(size_t)wave * OUT + lane] = acc - v - __logf(s);
}

extern "C" void kernel_launch(void* const* d_in, const int* in_sizes, int n_in,
                              void* d_out, int out_size, void* d_ws, size_t ws_size,
                              hipStream_t stream) {
    const float* x  = (const float*)d_in[0];
    const int*   ei = (const int*)d_in[1];
    const float* W1 = (const float*)d_in[2];
    const float* b1 = (const float*)d_in[3];
    const float* W2 = (const float*)d_in[4];
    const float* b2 = (const float*)d_in[5];
    float* y = (float*)d_out;

    const int HID = in_sizes[3];            // 64
    const int IN  = in_sizes[2] / HID;      // 256
    const int OUT = in_sizes[5];            // 40
    const int N   = in_sizes[0] / IN;       // 100000
    const int E   = in_sizes[1] / 2;        // 1600000
    const int* rowI = ei;
    const int* colI = ei + E;

    // workspace carve-up (all f32 except deg)
    float* p = (float*)d_ws;
    float* dis   = p;  p += N;
    float* segM  = p;  p += N;
    float* alpha = p;  p += N;
    float* Mbuf  = p;  p += E;
    float* h     = p;  p += (size_t)N * HID;   // also final-iteration output buffer
    float* outA  = p;  p += (size_t)N * HID;
    int*   deg   = (int*)p;

    const size_t NH = (size_t)N * HID;
    const int TPB = 256;
    const int edgeWaveBlocks = (E + 3) / 4;    // 4 waves/block
    const int rowWaveBlocks  = (N + 3) / 4;

    // degree + inv-sqrt
    hipMemsetAsync(deg, 0, sizeof(int) * N, stream);
    k_deg<<<(E + TPB - 1) / TPB, TPB, 0, stream>>>(colI, deg, E);
    k_dis<<<(N + TPB - 1) / TPB, TPB, 0, stream>>>(deg, dis, N);

    // front MLP
    k_mlp1<<<(N + 15) / 16, TPB, 0, stream>>>(x, W1, b1, h, N);

    // iteration 1: cur = h -> outA
    hipMemsetAsync(segM, 0, sizeof(float) * N, stream);
    k_calcM<<<edgeWaveBlocks, TPB, 0, stream>>>(rowI, colI, dis, h, Mbuf, segM, E);
    k_alpha<<<(N + TPB - 1) / TPB, TPB, 0, stream>>>(dis, segM, alpha, N);
    k_init<<<(int)((NH + TPB - 1) / TPB), TPB, 0, stream>>>(alpha, h, outA, NH);
    k_scatter<<<edgeWaveBlocks, TPB, 0, stream>>>(rowI, colI, dis, alpha, Mbuf, h, outA, E);

    // iteration 2: cur = outA -> h (in-place beta*h init is element-wise safe)
    hipMemsetAsync(segM, 0, sizeof(float) * N, stream);
    k_calcM<<<edgeWaveBlocks, TPB, 0, stream>>>(rowI, colI, dis, outA, Mbuf, segM, E);
    k_alpha<<<(N + TPB - 1) / TPB, TPB, 0, stream>>>(dis, segM, alpha, N);
    k_init<<<(int)((NH + TPB - 1) / TPB), TPB, 0, stream>>>(alpha, h, h, NH);
    k_scatter<<<edgeWaveBlocks, TPB, 0, stream>>>(rowI, colI, dis, alpha, Mbuf, outA, h, E);

    // output head
    k_head<<<rowWaveBlocks, TPB, 0, stream>>>(h, W2, b2, y, N, OUT);
}

// Round 2
// 1369.280 us; speedup vs baseline: 1.3100x; 1.3100x over previous
//
#include <hip/hip_runtime.h>
#include <math.h>

// pGNN on MI355X. N=100000, E=1.6M, IN=256, HID=64, OUT=40. MU=0.1, P=2.5, K=2.
// Round 2: scatter -> CSR gather (kills the 102M float atomics that capped
// round 1's k_scatter at 2 TB/s RMW throughput).

#define HIDC 64

// ---------------- degree ----------------
__global__ void k_deg(const int* __restrict__ col, int* __restrict__ deg, int E) {
    int e = blockIdx.x * blockDim.x + threadIdx.x;
    if (e < E) atomicAdd(&deg[col[e]], 1);
}

// ---------------- per-node: dis + CSR segment alloc ----------------
// Segment order across nodes is irrelevant; a bump allocator replaces the scan.
__global__ void k_nodeinit(const int* __restrict__ deg, float* __restrict__ dis,
                           int* __restrict__ off, int* __restrict__ cursor,
                           int* __restrict__ counter, int N) {
    int i = blockIdx.x * blockDim.x + threadIdx.x;
    if (i < N) {
        int d = deg[i];
        dis[i] = (d > 0) ? rsqrtf((float)d) : 0.0f;
        int o = atomicAdd(counter, d);
        off[i] = o;
        cursor[i] = o;
    }
}

// ---------------- CSR fill ----------------
__global__ void k_fill(const int* __restrict__ row, const int* __restrict__ col,
                       int* __restrict__ cursor, int* __restrict__ csr_src, int E) {
    int e = blockIdx.x * blockDim.x + threadIdx.x;
    if (e < E) {
        int pos = atomicAdd(&cursor[col[e]], 1);
        csr_src[pos] = row[e];
    }
}

// ---------------- h = relu(x @ W1 + b1) ----------------
__global__ void k_mlp1(const float* __restrict__ x, const float* __restrict__ W1,
                       const float* __restrict__ b1, float* __restrict__ h, int N) {
    __shared__ float xs[16][257];
    const int tid = threadIdx.x;
    const int rowBase = blockIdx.x * 16;
    #pragma unroll
    for (int i = 0; i < 4; ++i) {
        int slot = tid + 256 * i;
        int rl = slot >> 6;
        int off = (slot & 63) * 4;
        int grow = rowBase + rl;
        float4 v = make_float4(0.f, 0.f, 0.f, 0.f);
        if (grow < N) v = *(const float4*)(x + (size_t)grow * 256 + off);
        xs[rl][off]     = v.x;
        xs[rl][off + 1] = v.y;
        xs[rl][off + 2] = v.z;
        xs[rl][off + 3] = v.w;
    }
    __syncthreads();
    const int rl = tid >> 4;
    const int c4 = (tid & 15) * 4;
    const int row = rowBase + rl;
    if (row >= N) return;
    float a0 = b1[c4], a1 = b1[c4 + 1], a2 = b1[c4 + 2], a3 = b1[c4 + 3];
    #pragma unroll 8
    for (int k = 0; k < 256; ++k) {
        float xv = xs[rl][k];
        float4 w = *(const float4*)(W1 + k * HIDC + c4);
        a0 = fmaf(xv, w.x, a0);
        a1 = fmaf(xv, w.y, a1);
        a2 = fmaf(xv, w.z, a2);
        a3 = fmaf(xv, w.w, a3);
    }
    float4 r;
    r.x = fmaxf(a0, 0.f); r.y = fmaxf(a1, 0.f);
    r.z = fmaxf(a2, 0.f); r.w = fmaxf(a3, 0.f);
    *(float4*)(h + (size_t)row * HIDC + c4) = r;
}

// ---------------- fused calc_M (wave per destination node) ----------------
// Computes per-incoming-edge M (in CSR order), segM, alpha, alpha*dis locally.
__global__ void k_calcM(const int* __restrict__ csr_src, const int* __restrict__ off,
                        const int* __restrict__ deg, const float* __restrict__ dis,
                        const float* __restrict__ cur, float* __restrict__ Mcsr,
                        float* __restrict__ alphaArr, float* __restrict__ ad, int N) {
    int wave = (int)((blockIdx.x * (size_t)blockDim.x + threadIdx.x) >> 6);
    int lane = threadIdx.x & 63;
    if (wave >= N) return;
    const int c = wave;
    const int o = off[c];
    const int dg = deg[c];
    const float dc = dis[c];
    const float curc = dc * cur[(size_t)c * HIDC + lane];
    float seg = 0.0f;
    for (int j = 0; j < dg; ++j) {
        int r = csr_src[o + j];                 // wave-uniform broadcast load
        float dr = dis[r];
        float d = fmaf(dr, cur[(size_t)r * HIDC + lane], -curc);
        float s = d * d;
        #pragma unroll
        for (int sh = 32; sh; sh >>= 1) s += __shfl_xor(s, sh, 64);
        float m = sqrtf(sqrtf(s));              // grad_norm^(P-2), P=2.5
        if (isinf(m)) m = 0.0f;
        if (lane == 0) Mcsr[o + j] = m;
        seg += m;
    }
    if (lane == 0) {
        float a = 1.0f / (dc * dc * seg + 0.08f);   // 2*MU/P = 0.08
        alphaArr[c] = a;
        ad[c] = a * dc;
    }
}

// ---------------- gather: out[c] = beta*h[c] + sum M_ * cur[src] ----------------
__global__ void k_gather(const int* __restrict__ csr_src, const int* __restrict__ off,
                         const int* __restrict__ deg, const float* __restrict__ dis,
                         const float* __restrict__ alphaArr, const float* __restrict__ ad,
                         const float* __restrict__ Mcsr, const float* __restrict__ cur,
                         const float* __restrict__ h, float* __restrict__ outNext, int N) {
    int wave = (int)((blockIdx.x * (size_t)blockDim.x + threadIdx.x) >> 6);
    int lane = threadIdx.x & 63;
    if (wave >= N) return;
    const int c = wave;
    const int o = off[c];
    const int dg = deg[c];
    const float dc = dis[c];
    float acc = 0.16f * alphaArr[c] * h[(size_t)c * HIDC + lane];   // 4*MU/P = 0.16
    for (int j = 0; j < dg; ++j) {
        int r = csr_src[o + j];
        float coef = ad[r] * Mcsr[o + j] * dc;
        acc = fmaf(coef, cur[(size_t)r * HIDC + lane], acc);
    }
    outNext[(size_t)c * HIDC + lane] = acc;
}

// ---------------- head: log_softmax(out @ W2 + b2) ----------------
__global__ void k_head(const float* __restrict__ out, const float* __restrict__ W2,
                       const float* __restrict__ b2, float* __restrict__ y,
                       int N, int OUT) {
    int wave = (int)((blockIdx.x * (size_t)blockDim.x + threadIdx.x) >> 6);
    int lane = threadIdx.x & 63;
    if (wave >= N) return;
    float acc = 0.0f;
    if (lane < OUT) {
        acc = b2[lane];
        #pragma unroll 8
        for (int k = 0; k < HIDC; ++k)
            acc = fmaf(out[(size_t)wave * HIDC + k], W2[k * OUT + lane], acc);
    }
    float v = (lane < OUT) ? acc : -INFINITY;
    #pragma unroll
    for (int sh = 32; sh; sh >>= 1) v = fmaxf(v, __shfl_xor(v, sh, 64));
    float ex = (lane < OUT) ? __expf(acc - v) : 0.0f;
    float s = ex;
    #pragma unroll
    for (int sh = 32; sh; sh >>= 1) s += __shfl_xor(s, sh, 64);
    if (lane < OUT) y[(size_t)wave * OUT + lane] = acc - v - __logf(s);
}

extern "C" void kernel_launch(void* const* d_in, const int* in_sizes, int n_in,
                              void* d_out, int out_size, void* d_ws, size_t ws_size,
                              hipStream_t stream) {
    const float* x  = (const float*)d_in[0];
    const int*   ei = (const int*)d_in[1];
    const float* W1 = (const float*)d_in[2];
    const float* b1 = (const float*)d_in[3];
    const float* W2 = (const float*)d_in[4];
    const float* b2 = (const float*)d_in[5];
    float* y = (float*)d_out;

    const int HID = in_sizes[3];            // 64
    const int IN  = in_sizes[2] / HID;      // 256
    const int OUT = in_sizes[5];            // 40
    const int N   = in_sizes[0] / IN;       // 100000
    const int E   = in_sizes[1] / 2;        // 1.6M
    const int* rowI = ei;
    const int* colI = ei + E;

    // workspace carve-up
    float* p = (float*)d_ws;
    float* dis   = p;  p += N;
    float* alpha = p;  p += N;
    float* ad    = p;  p += N;
    float* Mcsr  = p;  p += E;
    float* h     = p;  p += (size_t)N * HID;   // MLP out; also iter-2 output
    float* outA  = p;  p += (size_t)N * HID;   // iter-1 output
    int*   deg     = (int*)p;  p += N;
    int*   off     = (int*)p;  p += N;
    int*   cursor  = (int*)p;  p += N;
    int*   counter = (int*)p;  p += 1;
    int*   csr_src = (int*)p;  p += E;

    const int TPB = 256;
    const int edgeBlocks     = (E + TPB - 1) / TPB;
    const int nodeBlocks     = (N + TPB - 1) / TPB;
    const int nodeWaveBlocks = (N + 3) / 4;       // 4 waves/block, wave per node

    // CSR build (per-launch; no state carried across calls)
    hipMemsetAsync(deg, 0, sizeof(int) * N, stream);
    hipMemsetAsync(counter, 0, sizeof(int), stream);
    k_deg<<<edgeBlocks, TPB, 0, stream>>>(colI, deg, E);
    k_nodeinit<<<nodeBlocks, TPB, 0, stream>>>(deg, dis, off, cursor, counter, N);
    k_fill<<<edgeBlocks, TPB, 0, stream>>>(rowI, colI, cursor, csr_src, E);

    // front MLP
    k_mlp1<<<(N + 15) / 16, TPB, 0, stream>>>(x, W1, b1, h, N);

    // iteration 1: cur = h -> outA
    k_calcM<<<nodeWaveBlocks, TPB, 0, stream>>>(csr_src, off, deg, dis, h, Mcsr, alpha, ad, N);
    k_gather<<<nodeWaveBlocks, TPB, 0, stream>>>(csr_src, off, deg, dis, alpha, ad, Mcsr, h, h, outA, N);

    // iteration 2: cur = outA -> h (gather reads h[c]/writes h[c] in same thread: safe)
    k_calcM<<<nodeWaveBlocks, TPB, 0, stream>>>(csr_src, off, deg, dis, outA, Mcsr, alpha, ad, N);
    k_gather<<<nodeWaveBlocks, TPB, 0, stream>>>(csr_src, off, deg, dis, alpha, ad, Mcsr, outA, h, h, N);

    // output head
    k_head<<<nodeWaveBlocks, TPB, 0, stream>>>(h, W2, b2, y, N, OUT);
}

// Round 3
// 971.106 us; speedup vs baseline: 1.8472x; 1.4100x over previous
//
#include <hip/hip_runtime.h>
#include <math.h>

// pGNN on MI355X. N=100000, E=1.6M, IN=256, HID=64, OUT=40. MU=0.1, P=2.5, K=2.
// Round 3: calc_M/gather restructured to 4-edges-per-wave (16 lanes x float4 dims)
// to cut the per-edge butterfly-reduction VALU cost ~4x (round 2: VALUBusy=66%).
// Also: scur = dis*cur precomputed (fused into producers) removes per-edge dis[r]
// loads; iter-1 gather writes only the scaled output (raw never consumed).

#define HIDC 64

// ---------------- degree ----------------
__global__ void k_deg(const int* __restrict__ col, int* __restrict__ deg, int E) {
    int e = blockIdx.x * blockDim.x + threadIdx.x;
    if (e < E) atomicAdd(&deg[col[e]], 1);
}

// ---------------- per-node: dis + CSR segment alloc (bump allocator) ----------------
__global__ void k_nodeinit(const int* __restrict__ deg, float* __restrict__ dis,
                           int* __restrict__ off, int* __restrict__ cursor,
                           int* __restrict__ counter, int N) {
    int i = blockIdx.x * blockDim.x + threadIdx.x;
    if (i < N) {
        int d = deg[i];
        dis[i] = (d > 0) ? rsqrtf((float)d) : 0.0f;
        int o = atomicAdd(counter, d);
        off[i] = o;
        cursor[i] = o;
    }
}

// ---------------- CSR fill ----------------
__global__ void k_fill(const int* __restrict__ row, const int* __restrict__ col,
                       int* __restrict__ cursor, int* __restrict__ csr_src, int E) {
    int e = blockIdx.x * blockDim.x + threadIdx.x;
    if (e < E) {
        int pos = atomicAdd(&cursor[col[e]], 1);
        csr_src[pos] = row[e];
    }
}

// ---------------- h = relu(x @ W1 + b1); sh = dis*h ----------------
__global__ void k_mlp1(const float* __restrict__ x, const float* __restrict__ W1,
                       const float* __restrict__ b1, const float* __restrict__ dis,
                       float* __restrict__ h, float* __restrict__ sh, int N) {
    __shared__ float xs[16][257];
    const int tid = threadIdx.x;
    const int rowBase = blockIdx.x * 16;
    #pragma unroll
    for (int i = 0; i < 4; ++i) {
        int slot = tid + 256 * i;
        int rl = slot >> 6;
        int off = (slot & 63) * 4;
        int grow = rowBase + rl;
        float4 v = make_float4(0.f, 0.f, 0.f, 0.f);
        if (grow < N) v = *(const float4*)(x + (size_t)grow * 256 + off);
        xs[rl][off]     = v.x;
        xs[rl][off + 1] = v.y;
        xs[rl][off + 2] = v.z;
        xs[rl][off + 3] = v.w;
    }
    __syncthreads();
    const int rl = tid >> 4;
    const int c4 = (tid & 15) * 4;
    const int row = rowBase + rl;
    if (row >= N) return;
    float a0 = b1[c4], a1 = b1[c4 + 1], a2 = b1[c4 + 2], a3 = b1[c4 + 3];
    #pragma unroll 8
    for (int k = 0; k < 256; ++k) {
        float xv = xs[rl][k];
        float4 w = *(const float4*)(W1 + k * HIDC + c4);
        a0 = fmaf(xv, w.x, a0);
        a1 = fmaf(xv, w.y, a1);
        a2 = fmaf(xv, w.z, a2);
        a3 = fmaf(xv, w.w, a3);
    }
    float4 r;
    r.x = fmaxf(a0, 0.f); r.y = fmaxf(a1, 0.f);
    r.z = fmaxf(a2, 0.f); r.w = fmaxf(a3, 0.f);
    *(float4*)(h + (size_t)row * HIDC + c4) = r;
    float dr = dis[row];
    float4 s = make_float4(r.x * dr, r.y * dr, r.z * dr, r.w * dr);
    *(float4*)(sh + (size_t)row * HIDC + c4) = s;
}

// ---------------- calc_M: wave per dest node, 4 edges/step, float4 dims ----------------
// diff = scur[r] - scur[c]; M = ||diff||^(P-2) = sqrt(sqrt(sum d^2)); alpha fused.
__global__ void k_calcM(const int* __restrict__ csr_src, const int* __restrict__ off,
                        const int* __restrict__ deg, const float* __restrict__ dis,
                        const float* __restrict__ scur, float* __restrict__ Mcsr,
                        float* __restrict__ alphaArr, int N) {
    int wave = (int)((blockIdx.x * (size_t)blockDim.x + threadIdx.x) >> 6);
    int lane = threadIdx.x & 63;
    if (wave >= N) return;
    const int c = wave;
    const int o = off[c];
    const int dg = deg[c];
    const int g = lane >> 4;     // edge group 0..3
    const int t = lane & 15;     // dim quad
    const float dc = dis[c];
    const float4 sc = *(const float4*)(scur + (size_t)c * HIDC + t * 4);
    float seg = 0.0f;
    for (int j = 0; j < dg; j += 4) {
        int jj = j + g;
        bool valid = jj < dg;
        int r = valid ? csr_src[o + jj] : c;     // r=c -> diff 0 for pad lanes
        const float4 sr = *(const float4*)(scur + (size_t)r * HIDC + t * 4);
        float dx = sr.x - sc.x, dy = sr.y - sc.y, dz = sr.z - sc.z, dw = sr.w - sc.w;
        float s = fmaf(dx, dx, fmaf(dy, dy, fmaf(dz, dz, dw * dw)));
        s += __shfl_xor(s, 1, 64);
        s += __shfl_xor(s, 2, 64);
        s += __shfl_xor(s, 4, 64);
        s += __shfl_xor(s, 8, 64);
        float m = sqrtf(sqrtf(s));               // grad_norm^(P-2), P=2.5
        if (isinf(m)) m = 0.0f;
        if (valid) {
            if (t == 0) Mcsr[o + jj] = m;
            seg += m;
        }
    }
    seg += __shfl_xor(seg, 16, 64);
    seg += __shfl_xor(seg, 32, 64);
    if (lane == 0) alphaArr[c] = 1.0f / (dc * dc * seg + 0.08f);   // 2*MU/P
}

// ---------------- gather: out[c] = beta*h[c] + sum (alpha[r]*M*dc) * scur[r] ----------------
// Writes raw out (outNext) and/or scaled out (soutNext = dis*out); either may be null.
__global__ void k_gather(const int* __restrict__ csr_src, const int* __restrict__ off,
                         const int* __restrict__ deg, const float* __restrict__ dis,
                         const float* __restrict__ alphaArr, const float* __restrict__ Mcsr,
                         const float* __restrict__ scur, const float* __restrict__ h,
                         float* __restrict__ outNext, float* __restrict__ soutNext, int N) {
    int wave = (int)((blockIdx.x * (size_t)blockDim.x + threadIdx.x) >> 6);
    int lane = threadIdx.x & 63;
    if (wave >= N) return;
    const int c = wave;
    const int o = off[c];
    const int dg = deg[c];
    const int g = lane >> 4;
    const int t = lane & 15;
    const float dc = dis[c];
    float4 acc = make_float4(0.f, 0.f, 0.f, 0.f);
    for (int j = 0; j < dg; j += 4) {
        int jj = j + g;
        bool valid = jj < dg;
        int r = valid ? csr_src[o + jj] : c;
        float coef = valid ? (alphaArr[r] * Mcsr[o + jj] * dc) : 0.0f;
        const float4 sr = *(const float4*)(scur + (size_t)r * HIDC + t * 4);
        acc.x = fmaf(coef, sr.x, acc.x);
        acc.y = fmaf(coef, sr.y, acc.y);
        acc.z = fmaf(coef, sr.z, acc.z);
        acc.w = fmaf(coef, sr.w, acc.w);
    }
    acc.x += __shfl_xor(acc.x, 16, 64);
    acc.y += __shfl_xor(acc.y, 16, 64);
    acc.z += __shfl_xor(acc.z, 16, 64);
    acc.w += __shfl_xor(acc.w, 16, 64);
    acc.x += __shfl_xor(acc.x, 32, 64);
    acc.y += __shfl_xor(acc.y, 32, 64);
    acc.z += __shfl_xor(acc.z, 32, 64);
    acc.w += __shfl_xor(acc.w, 32, 64);
    if (g == 0) {
        float ba = 0.16f * alphaArr[c];          // beta = 4*MU/P * alpha
        const float4 hv = *(const float4*)(h + (size_t)c * HIDC + t * 4);
        float4 ov;
        ov.x = fmaf(ba, hv.x, acc.x);
        ov.y = fmaf(ba, hv.y, acc.y);
        ov.z = fmaf(ba, hv.z, acc.z);
        ov.w = fmaf(ba, hv.w, acc.w);
        if (outNext)  *(float4*)(outNext  + (size_t)c * HIDC + t * 4) = ov;
        if (soutNext) {
            float4 sv = make_float4(ov.x * dc, ov.y * dc, ov.z * dc, ov.w * dc);
            *(float4*)(soutNext + (size_t)c * HIDC + t * 4) = sv;
        }
    }
}

// ---------------- head: log_softmax(out @ W2 + b2) ----------------
__global__ void k_head(const float* __restrict__ out, const float* __restrict__ W2,
                       const float* __restrict__ b2, float* __restrict__ y,
                       int N, int OUT) {
    int wave = (int)((blockIdx.x * (size_t)blockDim.x + threadIdx.x) >> 6);
    int lane = threadIdx.x & 63;
    if (wave >= N) return;
    float acc = 0.0f;
    if (lane < OUT) {
        acc = b2[lane];
        #pragma unroll 8
        for (int k = 0; k < HIDC; ++k)
            acc = fmaf(out[(size_t)wave * HIDC + k], W2[k * OUT + lane], acc);
    }
    float v = (lane < OUT) ? acc : -INFINITY;
    #pragma unroll
    for (int sh = 32; sh; sh >>= 1) v = fmaxf(v, __shfl_xor(v, sh, 64));
    float ex = (lane < OUT) ? __expf(acc - v) : 0.0f;
    float s = ex;
    #pragma unroll
    for (int sh = 32; sh; sh >>= 1) s += __shfl_xor(s, sh, 64);
    if (lane < OUT) y[(size_t)wave * OUT + lane] = acc - v - __logf(s);
}

extern "C" void kernel_launch(void* const* d_in, const int* in_sizes, int n_in,
                              void* d_out, int out_size, void* d_ws, size_t ws_size,
                              hipStream_t stream) {
    const float* x  = (const float*)d_in[0];
    const int*   ei = (const int*)d_in[1];
    const float* W1 = (const float*)d_in[2];
    const float* b1 = (const float*)d_in[3];
    const float* W2 = (const float*)d_in[4];
    const float* b2 = (const float*)d_in[5];
    float* y = (float*)d_out;

    const int HID = in_sizes[3];            // 64
    const int IN  = in_sizes[2] / HID;      // 256
    const int OUT = in_sizes[5];            // 40
    const int N   = in_sizes[0] / IN;       // 100000
    const int E   = in_sizes[1] / 2;        // 1.6M
    const int* rowI = ei;
    const int* colI = ei + E;

    // workspace carve-up
    float* p = (float*)d_ws;
    float* dis   = p;  p += N;
    float* alpha = p;  p += N;
    float* Mcsr  = p;  p += E;
    float* h     = p;  p += (size_t)N * HID;   // raw MLP out (beta term, both iters)
    float* sh    = p;  p += (size_t)N * HID;   // dis*h; reused as final out2
    float* sA    = p;  p += (size_t)N * HID;   // dis*out1
    int*   deg     = (int*)p;  p += N;
    int*   off     = (int*)p;  p += N;
    int*   cursor  = (int*)p;  p += N;
    int*   counter = (int*)p;  p += 1;
    int*   csr_src = (int*)p;  p += E;
    float* out2 = sh;                          // sh dead after iter-1 gather

    const int TPB = 256;
    const int edgeBlocks     = (E + TPB - 1) / TPB;
    const int nodeBlocks     = (N + TPB - 1) / TPB;
    const int nodeWaveBlocks = (N + 3) / 4;    // 4 waves/block, wave per node

    // CSR build
    hipMemsetAsync(deg, 0, sizeof(int) * N, stream);
    hipMemsetAsync(counter, 0, sizeof(int), stream);
    k_deg<<<edgeBlocks, TPB, 0, stream>>>(colI, deg, E);
    k_nodeinit<<<nodeBlocks, TPB, 0, stream>>>(deg, dis, off, cursor, counter, N);
    k_fill<<<edgeBlocks, TPB, 0, stream>>>(rowI, colI, cursor, csr_src, E);

    // front MLP (writes h and sh = dis*h)
    k_mlp1<<<(N + 15) / 16, TPB, 0, stream>>>(x, W1, b1, dis, h, sh, N);

    // iteration 1: scur = sh -> writes only sA (raw out1 never consumed)
    k_calcM<<<nodeWaveBlocks, TPB, 0, stream>>>(csr_src, off, deg, dis, sh, Mcsr, alpha, N);
    k_gather<<<nodeWaveBlocks, TPB, 0, stream>>>(csr_src, off, deg, dis, alpha, Mcsr,
                                                 sh, h, (float*)nullptr, sA, N);

    // iteration 2: scur = sA -> writes raw out2 (into sh's storage)
    k_calcM<<<nodeWaveBlocks, TPB, 0, stream>>>(csr_src, off, deg, dis, sA, Mcsr, alpha, N);
    k_gather<<<nodeWaveBlocks, TPB, 0, stream>>>(csr_src, off, deg, dis, alpha, Mcsr,
                                                 sA, h, out2, (float*)nullptr, N);

    // output head
    k_head<<<nodeWaveBlocks, TPB, 0, stream>>>(out2, W2, b2, y, N, OUT);
}